// Round 4
// baseline (61.861 us; speedup 1.0000x reference)
//
#include <hip/hip_runtime.h>
#include <hip/hip_bf16.h>

// RMSNorm over last dim D=2048, rows = B*S = 16384, fp32 in/out.
// out[r][d] = x[r][d] * rsqrt(mean(x[r]^2) + 5e-6) * gamma[r][d]
//
// R4: wave-per-row, barrier-free.
//  - Each 64-lane wave owns one full row: 8 float4 of x + 8 of g per lane.
//  - Butterfly __shfl_xor reduction -> every lane holds the row sum.
//    No LDS, no __syncthreads, 4 independent rows per 256-thread block.
//  - 16 loads issued back-to-back per thread (256 B in flight/lane).
//  - nt stores kept (L2 hygiene; proven no L3 effect -- FETCH invariant
//    at 128 MiB across plain/nt/partitioned variants R1-R3).

#define D_DIM 2048
#define VEC_PER_ROW (D_DIM / 4)   // 512 float4 per row
#define EPS 5e-6f

typedef float f32x4 __attribute__((ext_vector_type(4)));

__global__ __launch_bounds__(256) void rmsnorm_wave_kernel(
    const float4* __restrict__ x,
    const float4* __restrict__ g,
    float4* __restrict__ out)
{
    const int lane = threadIdx.x & 63;
    const int wv   = threadIdx.x >> 6;
    const long row = (long)blockIdx.x * 4 + wv;
    const long base = row * VEC_PER_ROW;

    // Issue all 16 loads up front (x then gamma), fully coalesced:
    // each instruction moves 64 lanes x 16 B = 1 KiB contiguous.
    float4 xv[8], gv[8];
    #pragma unroll
    for (int k = 0; k < 8; ++k) xv[k] = x[base + lane + 64 * k];
    #pragma unroll
    for (int k = 0; k < 8; ++k) gv[k] = g[base + lane + 64 * k];

    float ss = 0.0f;
    #pragma unroll
    for (int k = 0; k < 8; ++k) {
        ss += xv[k].x * xv[k].x + xv[k].y * xv[k].y
            + xv[k].z * xv[k].z + xv[k].w * xv[k].w;
    }

    // Wave-64 butterfly reduction: every lane ends with the full row sum.
    #pragma unroll
    for (int off = 32; off > 0; off >>= 1)
        ss += __shfl_xor(ss, off, 64);

    const float inv = rsqrtf(ss * (1.0f / (float)D_DIM) + EPS);

    #pragma unroll
    for (int k = 0; k < 8; ++k) {
        float4 o;
        o.x = xv[k].x * inv * gv[k].x;
        o.y = xv[k].y * inv * gv[k].y;
        o.z = xv[k].z * inv * gv[k].z;
        o.w = xv[k].w * inv * gv[k].w;
        __builtin_nontemporal_store(*(const f32x4*)&o,
                                    (f32x4*)&out[base + lane + 64 * k]);
    }
}

extern "C" void kernel_launch(void* const* d_in, const int* in_sizes, int n_in,
                              void* d_out, int out_size, void* d_ws, size_t ws_size,
                              hipStream_t stream) {
    const float* x = (const float*)d_in[0];
    const float* g = (const float*)d_in[1];
    float* out = (float*)d_out;

    const int rows = out_size / D_DIM;        // 4*4096 = 16384
    const int blocks = rows / 4;              // 4 rows (waves) per block
    rmsnorm_wave_kernel<<<blocks, 256, 0, stream>>>(
        (const float4*)x, (const float4*)g, (float4*)out);
}